// Round 2
// baseline (922.116 us; speedup 1.0000x reference)
//
#include <hip/hip_runtime.h>

// ---------------------------------------------------------------------------
// AdaptiveCompressionLayer: route rows to 1 of 3 experts, per-expert fused
//   C = X@Wc+bc (LDS, bf16) ; y = C@Wd+bd ; LayerNorm(y) -> out
// Inputs fp32; internal GEMMs bf16 MFMA (threshold 1.125e-01 allows it).
// ---------------------------------------------------------------------------

#define HDIM  768
#define SROWS 65536

using f32x4  = __attribute__((ext_vector_type(4))) float;
using bf16x8 = __attribute__((ext_vector_type(8))) short;

__device__ __forceinline__ unsigned short f2bf(float f) {
  union { float f; unsigned u; } c; c.f = f;
  unsigned r = (c.u + 0x7FFFu + ((c.u >> 16) & 1u)) >> 16;  // RNE
  return (unsigned short)r;
}

// ---------------- routing: per-row expert id -> compacted row lists --------
__global__ void route_kernel(const float* __restrict__ imp,
                             int* __restrict__ cnt, int* __restrict__ rowmap) {
  __shared__ int lc[3];
  __shared__ int lbase[3];
  const int t = threadIdx.x;
  const int r = blockIdx.x * 256 + t;
  if (t < 3) lc[t] = 0;
  __syncthreads();
  const float s = imp[r];
  const int e = (s > 0.8f) ? 0 : ((s > 0.4f) ? 1 : 2);
  const int lp = atomicAdd(&lc[e], 1);
  __syncthreads();
  if (t < 3) lbase[t] = atomicAdd(&cnt[t], lc[t]);
  __syncthreads();
  rowmap[e * SROWS + lbase[e] + lp] = r;
}

// ---------------- weights: transpose + zero-pad + fp32->bf16 ---------------
// dst[c][r] = (r<R && c<C) ? src[r][c] : 0 ;  dst is CP x RP (mult of 32)
struct TP { const float* src; unsigned short* dst; int R, C, CP, RP; };
struct TP6 { TP t[6]; };

__global__ void transpose_pad(TP6 p) {
  TP tp = p.t[blockIdx.z];
  const int r0 = blockIdx.x * 32;
  const int c0 = blockIdx.y * 32;
  if (r0 >= tp.RP || c0 >= tp.CP) return;
  __shared__ float tile[32][33];
  const int tx = threadIdx.x, ty = threadIdx.y;
#pragma unroll
  for (int k = 0; k < 4; ++k) {
    const int row = r0 + ty + k * 8, col = c0 + tx;
    tile[ty + k * 8][tx] =
        (row < tp.R && col < tp.C) ? tp.src[(size_t)row * tp.C + col] : 0.f;
  }
  __syncthreads();
#pragma unroll
  for (int k = 0; k < 4; ++k) {
    tp.dst[(size_t)(c0 + ty + k * 8) * tp.RP + (r0 + tx)] =
        f2bf(tile[tx][ty + k * 8]);
  }
}

// ---------------- fused per-expert kernel ----------------------------------
// block = 512 thr (8 waves), BM=32 rows.
// LDS: regionA = union(As[32][776], Bs2[768][40]) = 61440 B
//      Cs[32][HCP+8] bf16 ; Bs1[128][72] bf16 ; Ssum[32]+Ssq[32] f32
template <int HCP_, int HC_>
__global__ __launch_bounds__(512, 2)
void expert_gemm(const float* __restrict__ X, const float* __restrict__ bc,
                 const float* __restrict__ bd, const float* __restrict__ gamma,
                 const float* __restrict__ beta,
                 const unsigned short* __restrict__ WcT,   // [HCP][768]
                 const unsigned short* __restrict__ WdT,   // [768][HCP]
                 const int* __restrict__ cntE,
                 const int* __restrict__ rowmap,           // this expert's list
                 float* __restrict__ out) {
  const int n_rows = cntE[0];
  const int m0 = blockIdx.x * 32;
  if (m0 >= n_rows) return;
  const int rem = min(32, n_rows - m0);

  extern __shared__ char smem[];
  constexpr int CS_W = HCP_ + 8;
  unsigned short* As  = (unsigned short*)smem;                        // [32][776]
  unsigned short* Bs2 = (unsigned short*)smem;                        // [768][40]
  unsigned short* Cs  = (unsigned short*)(smem + 61440);              // [32][CS_W]
  unsigned short* Bs1 = (unsigned short*)(smem + 61440 + 32 * CS_W * 2); // [128][72]
  float* Ssum = (float*)(smem + 61440 + 32 * CS_W * 2 + 18432);
  float* Ssq  = Ssum + 32;

  const int tid  = threadIdx.x;
  const int wave = tid >> 6;
  const int lane = tid & 63;
  const int lhi  = lane >> 4;   // 0..3
  const int llo  = lane & 15;

  if (tid < 64) Ssum[tid] = 0.f;   // zeroes Ssum+Ssq (visible after 1st barrier)

  // ---- stage As: gathered X rows, fp32 -> bf16 ----
  {
    const int m = tid >> 4;        // 0..31
    const int q = tid & 15;
    const bool valid = (m < rem);
    const float* src = valid ? (X + (size_t)rowmap[m0 + m] * HDIM) : X;
    unsigned short* dstrow = As + m * 776;
#pragma unroll
    for (int i = 0; i < 12; ++i) {
      const int c4 = q + i * 16;   // float4 index, 0..191
      float4 v = make_float4(0.f, 0.f, 0.f, 0.f);
      if (valid) v = reinterpret_cast<const float4*>(src)[c4];
      ushort4 b;
      b.x = f2bf(v.x); b.y = f2bf(v.y); b.z = f2bf(v.z); b.w = f2bf(v.w);
      *reinterpret_cast<ushort4*>(dstrow + c4 * 4) = b;
    }
  }
  __syncthreads();

  // ---- GEMM1: Cs[32][HCP] = As @ WcT^T + bc ----
  constexpr int NT1 = (HCP_ + 127) / 128;
#pragma unroll 1
  for (int nt = 0; nt < NT1; ++nt) {
    const int n0 = nt * 128;
    f32x4 acc0 = {0.f, 0.f, 0.f, 0.f};
    f32x4 acc1 = {0.f, 0.f, 0.f, 0.f};
    for (int k0 = 0; k0 < HDIM; k0 += 64) {
      __syncthreads();
#pragma unroll
      for (int j = 0; j < 2; ++j) {     // Bs1[128][64] <- WcT rows n0..n0+127
        const int idx = tid + j * 512;  // 0..1023
        const int row = idx >> 3, seg = idx & 7;
        int srow = n0 + row; if (srow >= HCP_) srow = HCP_ - 1;  // clamp (guarded later)
        *reinterpret_cast<bf16x8*>(Bs1 + row * 72 + seg * 8) =
            *reinterpret_cast<const bf16x8*>(WcT + (size_t)srow * HDIM + k0 + seg * 8);
      }
      __syncthreads();
#pragma unroll
      for (int ks = 0; ks < 2; ++ks) {
        bf16x8 a0 = *reinterpret_cast<const bf16x8*>(As + llo * 776 + k0 + ks * 32 + lhi * 8);
        bf16x8 a1 = *reinterpret_cast<const bf16x8*>(As + (16 + llo) * 776 + k0 + ks * 32 + lhi * 8);
        bf16x8 b  = *reinterpret_cast<const bf16x8*>(Bs1 + (wave * 16 + llo) * 72 + ks * 32 + lhi * 8);
        acc0 = __builtin_amdgcn_mfma_f32_16x16x32_bf16(a0, b, acc0, 0, 0, 0);
        acc1 = __builtin_amdgcn_mfma_f32_16x16x32_bf16(a1, b, acc1, 0, 0, 0);
      }
    }
    const int ncol = n0 + wave * 16 + llo;   // D: col = lane&15, row = (lane>>4)*4+r
    if (ncol < HCP_) {
      const float bcv = (ncol < HC_) ? bc[ncol] : 0.f;  // pad cols stay exactly 0
#pragma unroll
      for (int r = 0; r < 4; ++r) {
        Cs[(lhi * 4 + r) * CS_W + ncol]        = f2bf(acc0[r] + bcv);
        Cs[(16 + lhi * 4 + r) * CS_W + ncol]   = f2bf(acc1[r] + bcv);
      }
    }
  }
  __syncthreads();   // Cs complete; As dead -> Bs2 may overwrite regionA

  // ---- GEMM2: y[32][768] = Cs @ WdT^T ; fused bias + LayerNorm ----
  f32x4 y[2][6];
#pragma unroll
  for (int mi = 0; mi < 2; ++mi)
#pragma unroll
    for (int j = 0; j < 6; ++j) y[mi][j] = f32x4{0.f, 0.f, 0.f, 0.f};

#pragma unroll 1
  for (int k0 = 0; k0 < HCP_; k0 += 32) {
#pragma unroll
    for (int j = 0; j < 6; ++j) {       // Bs2[768][32] <- WdT[:, k0..k0+32)
      const int idx = tid + j * 512;    // 0..3071
      const int row = idx >> 2, seg = idx & 3;
      *reinterpret_cast<bf16x8*>(Bs2 + row * 40 + seg * 8) =
          *reinterpret_cast<const bf16x8*>(WdT + (size_t)row * HCP_ + k0 + seg * 8);
    }
    __syncthreads();
    bf16x8 a0 = *reinterpret_cast<const bf16x8*>(Cs + llo * CS_W + k0 + lhi * 8);
    bf16x8 a1 = *reinterpret_cast<const bf16x8*>(Cs + (16 + llo) * CS_W + k0 + lhi * 8);
#pragma unroll
    for (int j = 0; j < 6; ++j) {
      bf16x8 b = *reinterpret_cast<const bf16x8*>(Bs2 + (wave * 96 + j * 16 + llo) * 40 + lhi * 8);
      y[0][j] = __builtin_amdgcn_mfma_f32_16x16x32_bf16(a0, b, y[0][j], 0, 0, 0);
      y[1][j] = __builtin_amdgcn_mfma_f32_16x16x32_bf16(a1, b, y[1][j], 0, 0, 0);
    }
    __syncthreads();
  }

  const int nb = wave * 96;
#pragma unroll
  for (int j = 0; j < 6; ++j) {          // + bd
    const float bdv = bd[nb + j * 16 + llo];
#pragma unroll
    for (int mi = 0; mi < 2; ++mi)
#pragma unroll
      for (int r = 0; r < 4; ++r) y[mi][j][r] += bdv;
  }

  // per-row partial sums over this wave's 96 cols, reduce across 16 lanes
#pragma unroll
  for (int mi = 0; mi < 2; ++mi)
#pragma unroll
    for (int r = 0; r < 4; ++r) {
      float s = 0.f, q = 0.f;
#pragma unroll
      for (int j = 0; j < 6; ++j) {
        const float v = y[mi][j][r];
        s += v; q += v * v;
      }
#pragma unroll
      for (int d = 1; d < 16; d <<= 1) {
        s += __shfl_xor(s, d);
        q += __shfl_xor(q, d);
      }
      if (llo == 0) {
        atomicAdd(&Ssum[mi * 16 + lhi * 4 + r], s);
        atomicAdd(&Ssq [mi * 16 + lhi * 4 + r], q);
      }
    }
  __syncthreads();

#pragma unroll
  for (int mi = 0; mi < 2; ++mi)
#pragma unroll
    for (int r = 0; r < 4; ++r) {
      const int row = mi * 16 + lhi * 4 + r;
      if (row < rem) {
        const float mean = Ssum[row] * (1.0f / 768.0f);
        const float var  = Ssq[row] * (1.0f / 768.0f) - mean * mean;
        const float rstd = rsqrtf(var + 1e-5f);
        const int orow = rowmap[m0 + row];
        float* op = out + (size_t)orow * HDIM;
#pragma unroll
        for (int j = 0; j < 6; ++j) {
          const int n = nb + j * 16 + llo;
          op[n] = (y[mi][j][r] - mean) * rstd * gamma[n] + beta[n];
        }
      }
    }
}

// ---------------------------------------------------------------------------
extern "C" void kernel_launch(void* const* d_in, const int* in_sizes, int n_in,
                              void* d_out, int out_size, void* d_ws, size_t ws_size,
                              hipStream_t stream) {
  const float* X     = (const float*)d_in[0];
  const float* imp   = (const float*)d_in[1];
  const float* Wc0   = (const float*)d_in[2];
  const float* bc0   = (const float*)d_in[3];
  const float* Wd0   = (const float*)d_in[4];
  const float* bd0   = (const float*)d_in[5];
  const float* Wc1   = (const float*)d_in[6];
  const float* bc1   = (const float*)d_in[7];
  const float* Wd1   = (const float*)d_in[8];
  const float* bd1   = (const float*)d_in[9];
  const float* Wc2   = (const float*)d_in[10];
  const float* bc2   = (const float*)d_in[11];
  const float* Wd2   = (const float*)d_in[12];
  const float* bd2   = (const float*)d_in[13];
  const float* gamma = (const float*)d_in[14];
  const float* beta  = (const float*)d_in[15];
  float* out = (float*)d_out;
  char* ws = (char*)d_ws;

  // ws layout (all 512-aligned): counters | rowmap[3*S] | WcT* | WdT*  (~4.7MB)
  int* cnt    = (int*)ws;
  int* rowmap = (int*)(ws + 512);
  unsigned short* WcT0 = (unsigned short*)(ws + 787456);
  unsigned short* WcT1 = WcT0 + 704 * 768;
  unsigned short* WcT2 = WcT1 + 544 * 768;
  unsigned short* WdT0 = WcT2 + 96 * 768;
  unsigned short* WdT1 = WdT0 + 768 * 704;
  unsigned short* WdT2 = WdT1 + 768 * 544;

  hipMemsetAsync(cnt, 0, 16, stream);
  route_kernel<<<SROWS / 256, 256, 0, stream>>>(imp, cnt, rowmap);

  TP6 p;
  p.t[0] = {Wc0, WcT0, 768, 691, 704, 768};
  p.t[1] = {Wc1, WcT1, 768, 537, 544, 768};
  p.t[2] = {Wc2, WcT2, 768, 76, 96, 768};
  p.t[3] = {Wd0, WdT0, 691, 768, 768, 704};
  p.t[4] = {Wd1, WdT1, 537, 768, 768, 544};
  p.t[5] = {Wd2, WdT2, 76, 768, 768, 96};
  transpose_pad<<<dim3(24, 24, 6), dim3(32, 8), 0, stream>>>(p);

  constexpr int SM0 = 61440 + 32 * (704 + 8) * 2 + 18432 + 256;  // 125696
  constexpr int SM1 = 61440 + 32 * (544 + 8) * 2 + 18432 + 256;  // 115456
  constexpr int SM2 = 61440 + 32 * (96 + 8) * 2 + 18432 + 256;   //  86784
  (void)hipFuncSetAttribute((const void*)expert_gemm<704, 691>,
                            hipFuncAttributeMaxDynamicSharedMemorySize, SM0);
  (void)hipFuncSetAttribute((const void*)expert_gemm<544, 537>,
                            hipFuncAttributeMaxDynamicSharedMemorySize, SM1);
  (void)hipFuncSetAttribute((const void*)expert_gemm<96, 76>,
                            hipFuncAttributeMaxDynamicSharedMemorySize, SM2);

  expert_gemm<704, 691><<<SROWS / 32, 512, SM0, stream>>>(
      X, bc0, bd0, gamma, beta, WcT0, WdT0, cnt + 0, rowmap + 0 * SROWS, out);
  expert_gemm<544, 537><<<SROWS / 32, 512, SM1, stream>>>(
      X, bc1, bd1, gamma, beta, WcT1, WdT1, cnt + 1, rowmap + 1 * SROWS, out);
  expert_gemm<96, 76><<<SROWS / 32, 512, SM2, stream>>>(
      X, bc2, bd2, gamma, beta, WcT2, WdT2, cnt + 2, rowmap + 2 * SROWS, out);
}

// Round 5
// 657.463 us; speedup vs baseline: 1.4025x; 1.4025x over previous
//
#include <hip/hip_runtime.h>

// ---------------------------------------------------------------------------
// AdaptiveCompressionLayer r3b: single fused kernel for all 3 experts
// (device-side block->expert mapping), 2-phase pipelined staging with raw
// s_barrier + counted waits so prefetch loads stay in flight across barriers.
// ---------------------------------------------------------------------------

#define HDIM  768
#define SROWS 65536

using f32x4  = __attribute__((ext_vector_type(4))) float;
using bf16x8 = __attribute__((ext_vector_type(8))) short;

__device__ __forceinline__ unsigned short f2bf(float f) {
  union { float f; unsigned u; } c; c.f = f;
  unsigned r = (c.u + 0x7FFFu + ((c.u >> 16) & 1u)) >> 16;  // RNE
  return (unsigned short)r;
}

// ---------------- routing: per-row expert id -> compacted row lists --------
__global__ void route_kernel(const float* __restrict__ imp,
                             int* __restrict__ cnt, int* __restrict__ rowmap) {
  __shared__ int lc[3];
  __shared__ int lbase[3];
  const int t = threadIdx.x;
  const int r = blockIdx.x * 256 + t;
  if (t < 3) lc[t] = 0;
  __syncthreads();
  const float s = imp[r];
  const int e = (s > 0.8f) ? 0 : ((s > 0.4f) ? 1 : 2);
  const int lp = atomicAdd(&lc[e], 1);
  __syncthreads();
  if (t < 3) lbase[t] = atomicAdd(&cnt[t], lc[t]);
  __syncthreads();
  rowmap[e * SROWS + lbase[e] + lp] = r;
}

// ---------------- weights: transpose + zero-pad + fp32->bf16 ---------------
struct TP { const float* src; unsigned short* dst; int R, C, CP, RP; };
struct TP6 { TP t[6]; };

__global__ void transpose_pad(TP6 p) {
  TP tp = p.t[blockIdx.z];
  const int r0 = blockIdx.x * 32;
  const int c0 = blockIdx.y * 32;
  if (r0 >= tp.RP || c0 >= tp.CP) return;
  __shared__ float tile[32][33];
  const int tx = threadIdx.x, ty = threadIdx.y;
#pragma unroll
  for (int k = 0; k < 4; ++k) {
    const int row = r0 + ty + k * 8, col = c0 + tx;
    tile[ty + k * 8][tx] =
        (row < tp.R && col < tp.C) ? tp.src[(size_t)row * tp.C + col] : 0.f;
  }
  __syncthreads();
#pragma unroll
  for (int k = 0; k < 4; ++k) {
    tp.dst[(size_t)(c0 + ty + k * 8) * tp.RP + (r0 + tx)] =
        f2bf(tile[tx][ty + k * 8]);
  }
}

// ---------------- per-expert fused body ------------------------------------
// block = 512 thr (8 waves), BM=32 rows.
// LDS: regionU = union(As[32][776], Bs2[768][40]) = 61440 B
//      Cs[32][HCP+8] bf16 ; Bs1[128][72] bf16 (single buf, reg-prefetch)
//      Ssum[32]+Ssq[32] f32
template <int HCP_, int HC_>
__device__ __forceinline__ void expert_body(
    char* smem, int t, int n_rows,
    const float* __restrict__ X, const float* __restrict__ bc,
    const float* __restrict__ bd, const float* __restrict__ gamma,
    const float* __restrict__ beta,
    const unsigned short* __restrict__ WcT,   // [HCP][768]
    const unsigned short* __restrict__ WdT,   // [768][HCP]
    const int* __restrict__ rowlist, float* __restrict__ out) {
  const int m0 = t * 32;
  const int rem = min(32, n_rows - m0);

  constexpr int CS_W = HCP_ + 8;
  unsigned short* As  = (unsigned short*)smem;                         // [32][776]
  unsigned short* Bs2 = (unsigned short*)smem;                         // [768][40]
  unsigned short* Cs  = (unsigned short*)(smem + 61440);               // [32][CS_W]
  unsigned short* Bs1 = (unsigned short*)(smem + 61440 + 32 * CS_W * 2); // [128][72]
  float* Ssum = (float*)(smem + 61440 + 32 * CS_W * 2 + 18432);
  float* Ssq  = Ssum + 32;

  const int tid  = threadIdx.x;
  const int wave = tid >> 6;
  const int lane = tid & 63;
  const int lhi  = lane >> 4;
  const int llo  = lane & 15;

  // ---- issue prefetch of GEMM1 tile (nt=0,kk=0) immediately ----
  const int pr = tid >> 3;   // 0..63  (row within 128-row tile, +64 for p1)
  const int ps = tid & 7;    // 16B segment
  bf16x8 p0 = *reinterpret_cast<const bf16x8*>(
      WcT + (size_t)min(pr, HCP_ - 1) * HDIM + ps * 8);
  bf16x8 p1 = *reinterpret_cast<const bf16x8*>(
      WcT + (size_t)min(64 + pr, HCP_ - 1) * HDIM + ps * 8);

  if (tid < 64) Ssum[tid] = 0.f;   // zeroes Ssum+Ssq

  // ---- stage As: gathered X rows, fp32 -> bf16 (one-time) ----
  {
    const int m = tid >> 4;
    const int q = tid & 15;
    const bool valid = (m < rem);
    const float* src = valid ? (X + (size_t)rowlist[m0 + m] * HDIM) : X;
    unsigned short* dstrow = As + m * 776;
#pragma unroll
    for (int i = 0; i < 12; ++i) {
      const int c4 = q + i * 16;
      float4 v = make_float4(0.f, 0.f, 0.f, 0.f);
      if (valid) v = reinterpret_cast<const float4*>(src)[c4];
      ushort4 b;
      b.x = f2bf(v.x); b.y = f2bf(v.y); b.z = f2bf(v.z); b.w = f2bf(v.w);
      *reinterpret_cast<ushort4*>(dstrow + c4 * 4) = b;
    }
  }
  asm volatile("s_waitcnt lgkmcnt(0)" ::: "memory");  // As + Ssum visible at barrier

  // ---- GEMM1: Cs[32][HCP] = As @ WcT^T + bc  (2-phase pipelined) ----
  constexpr int NT1 = (HCP_ + 127) / 128;
  constexpr int NS1 = NT1 * 12;
  f32x4 acc0 = {0.f, 0.f, 0.f, 0.f};
  f32x4 acc1 = {0.f, 0.f, 0.f, 0.f};
  int ntc = 0, kkc = 0, ntn = 0, kkn = 0;
#pragma unroll 1
  for (int s = 0; s < NS1; ++s) {
    __builtin_amdgcn_s_barrier();              // Bs1 consumers of prev tile done
    *reinterpret_cast<bf16x8*>(Bs1 + pr * 72 + ps * 8)        = p0;
    *reinterpret_cast<bf16x8*>(Bs1 + (64 + pr) * 72 + ps * 8) = p1;
    if (s + 1 < NS1) {                          // issue next-tile prefetch
      ++kkn; if (kkn == 12) { kkn = 0; ++ntn; }
      const unsigned short* wp = WcT + kkn * 64 + ps * 8;
      p0 = *reinterpret_cast<const bf16x8*>(
          wp + (size_t)min(ntn * 128 + pr, HCP_ - 1) * HDIM);
      p1 = *reinterpret_cast<const bf16x8*>(
          wp + (size_t)min(ntn * 128 + 64 + pr, HCP_ - 1) * HDIM);
    }
    asm volatile("s_waitcnt lgkmcnt(0)" ::: "memory");  // ds_writes done
    __builtin_amdgcn_s_barrier();              // Bs1 tile visible; vmcnt NOT drained
    const int k0 = kkc * 64;
#pragma unroll
    for (int ks = 0; ks < 2; ++ks) {
      bf16x8 a0 = *reinterpret_cast<const bf16x8*>(As + llo * 776 + k0 + ks * 32 + lhi * 8);
      bf16x8 a1 = *reinterpret_cast<const bf16x8*>(As + (16 + llo) * 776 + k0 + ks * 32 + lhi * 8);
      bf16x8 b  = *reinterpret_cast<const bf16x8*>(Bs1 + (wave * 16 + llo) * 72 + ks * 32 + lhi * 8);
      acc0 = __builtin_amdgcn_mfma_f32_16x16x32_bf16(a0, b, acc0, 0, 0, 0);
      acc1 = __builtin_amdgcn_mfma_f32_16x16x32_bf16(a1, b, acc1, 0, 0, 0);
    }
    if (kkc == 11) {                            // nt epilogue: write Cs
      const int ncol = ntc * 128 + wave * 16 + llo;
      if (ncol < HCP_) {
        const float bcv = (ncol < HC_) ? bc[ncol] : 0.f;
#pragma unroll
        for (int r = 0; r < 4; ++r) {
          Cs[(lhi * 4 + r) * CS_W + ncol]      = f2bf(acc0[r] + bcv);
          Cs[(16 + lhi * 4 + r) * CS_W + ncol] = f2bf(acc1[r] + bcv);
        }
      }
      acc0 = f32x4{0.f, 0.f, 0.f, 0.f};
      acc1 = f32x4{0.f, 0.f, 0.f, 0.f};
      kkc = 0; ++ntc;
    } else {
      ++kkc;
    }
  }
  asm volatile("s_waitcnt lgkmcnt(0)" ::: "memory");  // Cs writes done

  // ---- GEMM2: y[32][768] = Cs @ WdT^T  (2-phase pipelined, 48KB chunks) ----
  constexpr int NC = HCP_ / 32;
  f32x4 y[2][6];
#pragma unroll
  for (int mi = 0; mi < 2; ++mi)
#pragma unroll
    for (int j = 0; j < 6; ++j) y[mi][j] = f32x4{0.f, 0.f, 0.f, 0.f};

  bf16x8 q[6];
#pragma unroll
  for (int j = 0; j < 6; ++j) {                 // prefetch chunk 0
    const int idx = tid + j * 512;
    q[j] = *reinterpret_cast<const bf16x8*>(
        WdT + (size_t)(idx >> 2) * HCP_ + (idx & 3) * 8);
  }
#pragma unroll 1
  for (int c = 0; c < NC; ++c) {
    __builtin_amdgcn_s_barrier();               // prev chunk consumed / As dead
#pragma unroll
    for (int j = 0; j < 6; ++j) {
      const int idx = tid + j * 512;
      *reinterpret_cast<bf16x8*>(Bs2 + (idx >> 2) * 40 + (idx & 3) * 8) = q[j];
    }
    if (c + 1 < NC) {
#pragma unroll
      for (int j = 0; j < 6; ++j) {
        const int idx = tid + j * 512;
        q[j] = *reinterpret_cast<const bf16x8*>(
            WdT + (size_t)(idx >> 2) * HCP_ + (c + 1) * 32 + (idx & 3) * 8);
      }
    }
    asm volatile("s_waitcnt lgkmcnt(0)" ::: "memory");
    __builtin_amdgcn_s_barrier();
    const int k0 = c * 32;
    bf16x8 a0 = *reinterpret_cast<const bf16x8*>(Cs + llo * CS_W + k0 + lhi * 8);
    bf16x8 a1 = *reinterpret_cast<const bf16x8*>(Cs + (16 + llo) * CS_W + k0 + lhi * 8);
#pragma unroll
    for (int j = 0; j < 6; ++j) {
      bf16x8 b = *reinterpret_cast<const bf16x8*>(Bs2 + (wave * 96 + j * 16 + llo) * 40 + lhi * 8);
      y[0][j] = __builtin_amdgcn_mfma_f32_16x16x32_bf16(a0, b, y[0][j], 0, 0, 0);
      y[1][j] = __builtin_amdgcn_mfma_f32_16x16x32_bf16(a1, b, y[1][j], 0, 0, 0);
    }
  }

  // ---- epilogue: +bd, LayerNorm, store ----
  const int nb = wave * 96;
#pragma unroll
  for (int j = 0; j < 6; ++j) {
    const float bdv = bd[nb + j * 16 + llo];
#pragma unroll
    for (int mi = 0; mi < 2; ++mi)
#pragma unroll
      for (int r = 0; r < 4; ++r) y[mi][j][r] += bdv;
  }

#pragma unroll
  for (int mi = 0; mi < 2; ++mi)
#pragma unroll
    for (int r = 0; r < 4; ++r) {
      float s = 0.f, qq = 0.f;
#pragma unroll
      for (int j = 0; j < 6; ++j) {
        const float v = y[mi][j][r];
        s += v; qq += v * v;
      }
#pragma unroll
      for (int d = 1; d < 16; d <<= 1) {
        s  += __shfl_xor(s, d);
        qq += __shfl_xor(qq, d);
      }
      if (llo == 0) {
        atomicAdd(&Ssum[mi * 16 + lhi * 4 + r], s);
        atomicAdd(&Ssq [mi * 16 + lhi * 4 + r], qq);
      }
    }
  __syncthreads();

#pragma unroll
  for (int mi = 0; mi < 2; ++mi)
#pragma unroll
    for (int r = 0; r < 4; ++r) {
      const int row = mi * 16 + lhi * 4 + r;
      if (row < rem) {
        const float mean = Ssum[row] * (1.0f / 768.0f);
        const float var  = Ssq[row] * (1.0f / 768.0f) - mean * mean;
        const float rstd = rsqrtf(var + 1e-5f);
        const int orow = rowlist[m0 + row];
        float* op = out + (size_t)orow * HDIM;
#pragma unroll
        for (int j = 0; j < 6; ++j) {
          const int n = nb + j * 16 + llo;
          op[n] = (y[mi][j][r] - mean) * rstd * gamma[n] + beta[n];
        }
      }
    }
}

// ---------------- merged dispatch kernel -----------------------------------
__global__ __launch_bounds__(512, 2)
void fused_moe(const float* __restrict__ X,
               const float* __restrict__ bc0, const float* __restrict__ bd0,
               const float* __restrict__ bc1, const float* __restrict__ bd1,
               const float* __restrict__ bc2, const float* __restrict__ bd2,
               const float* __restrict__ gamma, const float* __restrict__ beta,
               const unsigned short* __restrict__ WcT0,
               const unsigned short* __restrict__ WcT1,
               const unsigned short* __restrict__ WcT2,
               const unsigned short* __restrict__ WdT0,
               const unsigned short* __restrict__ WdT1,
               const unsigned short* __restrict__ WdT2,
               const int* __restrict__ cnt, const int* __restrict__ rowmap,
               float* __restrict__ out) {
  extern __shared__ char smem[];
  const int c0 = cnt[0], c1 = cnt[1], c2 = cnt[2];
  const int nb0 = (c0 + 31) >> 5;
  const int nb1 = (c1 + 31) >> 5;
  const int nb2 = (c2 + 31) >> 5;
  const int wg = blockIdx.x;
  if (wg >= nb0 + nb1 + nb2) return;
  if (wg < nb0) {
    expert_body<704, 691>(smem, wg, c0, X, bc0, bd0, gamma, beta,
                          WcT0, WdT0, rowmap, out);
  } else if (wg < nb0 + nb1) {
    expert_body<544, 537>(smem, wg - nb0, c1, X, bc1, bd1, gamma, beta,
                          WcT1, WdT1, rowmap + SROWS, out);
  } else {
    expert_body<96, 76>(smem, wg - nb0 - nb1, c2, X, bc2, bd2, gamma, beta,
                        WcT2, WdT2, rowmap + 2 * SROWS, out);
  }
}

// ---------------------------------------------------------------------------
extern "C" void kernel_launch(void* const* d_in, const int* in_sizes, int n_in,
                              void* d_out, int out_size, void* d_ws, size_t ws_size,
                              hipStream_t stream) {
  const float* X     = (const float*)d_in[0];
  const float* imp   = (const float*)d_in[1];
  const float* Wc0   = (const float*)d_in[2];
  const float* bc0   = (const float*)d_in[3];
  const float* Wd0   = (const float*)d_in[4];
  const float* bd0   = (const float*)d_in[5];
  const float* Wc1   = (const float*)d_in[6];
  const float* bc1   = (const float*)d_in[7];
  const float* Wd1   = (const float*)d_in[8];
  const float* bd1   = (const float*)d_in[9];
  const float* Wc2   = (const float*)d_in[10];
  const float* bc2   = (const float*)d_in[11];
  const float* Wd2   = (const float*)d_in[12];
  const float* bd2   = (const float*)d_in[13];
  const float* gamma = (const float*)d_in[14];
  const float* beta  = (const float*)d_in[15];
  float* out = (float*)d_out;
  char* ws = (char*)d_ws;

  int* cnt    = (int*)ws;
  int* rowmap = (int*)(ws + 512);
  unsigned short* WcT0 = (unsigned short*)(ws + 787456);
  unsigned short* WcT1 = WcT0 + 704 * 768;
  unsigned short* WcT2 = WcT1 + 544 * 768;
  unsigned short* WdT0 = WcT2 + 96 * 768;
  unsigned short* WdT1 = WdT0 + 768 * 704;
  unsigned short* WdT2 = WdT1 + 768 * 544;

  hipMemsetAsync(cnt, 0, 16, stream);
  route_kernel<<<SROWS / 256, 256, 0, stream>>>(imp, cnt, rowmap);

  TP6 p;
  p.t[0] = {Wc0, WcT0, 768, 691, 704, 768};
  p.t[1] = {Wc1, WcT1, 768, 537, 544, 768};
  p.t[2] = {Wc2, WcT2, 768, 76, 96, 768};
  p.t[3] = {Wd0, WdT0, 691, 768, 768, 704};
  p.t[4] = {Wd1, WdT1, 537, 768, 768, 544};
  p.t[5] = {Wd2, WdT2, 76, 768, 768, 96};
  transpose_pad<<<dim3(24, 24, 6), dim3(32, 8), 0, stream>>>(p);

  // max LDS across instantiations: 61440 + 32*(704+8)*2 + 18432 + 256
  constexpr int SMEM_MAX = 61440 + 32 * (704 + 8) * 2 + 18432 + 256;  // 125696
  (void)hipFuncSetAttribute((const void*)fused_moe,
                            hipFuncAttributeMaxDynamicSharedMemorySize, SMEM_MAX);

  fused_moe<<<SROWS / 32 + 3, 512, SMEM_MAX, stream>>>(
      X, bc0, bd0, bc1, bd1, bc2, bd2, gamma, beta,
      WcT0, WcT1, WcT2, WdT0, WdT1, WdT2, cnt, rowmap, out);
}